// Round 1
// 837.074 us; speedup vs baseline: 1.1494x; 1.1494x over previous
//
#include <hip/hip_runtime.h>
#include <hip/hip_bf16.h>

// Problem sizes
#define BB 8
#define CCH 128
#define HH 256
#define WW2 256
#define NN 65536      // H*W
#define NP 16384      // 128*128 pooled
#define BN_EPS 1e-5f

typedef _Float16 half8 __attribute__((ext_vector_type(8)));
typedef _Float16 half4v __attribute__((ext_vector_type(4)));
typedef float floatx16 __attribute__((ext_vector_type(16)));

__device__ __forceinline__ floatx16 zero16() {
  floatx16 z;
#pragma unroll
  for (int i = 0; i < 16; i++) z[i] = 0.f;
  return z;
}

__device__ __forceinline__ floatx16 mfma16(half8 a, half8 b, floatx16 c) {
  return __builtin_amdgcn_mfma_f32_32x32x16_f16(a, b, c, 0, 0, 0);
}

// split 8 fp32 (two float4) into hi/lo fp16 pairs (gram phase)
__device__ __forceinline__ void split8(float4 a, float4 b, half8& h, half8& l) {
  float v0 = a.x, v1 = a.y, v2 = a.z, v3 = a.w;
  float v4 = b.x, v5 = b.y, v6 = b.z, v7 = b.w;
  h[0] = (_Float16)v0; h[1] = (_Float16)v1; h[2] = (_Float16)v2; h[3] = (_Float16)v3;
  h[4] = (_Float16)v4; h[5] = (_Float16)v5; h[6] = (_Float16)v6; h[7] = (_Float16)v7;
  l[0] = (_Float16)(v0 - (float)h[0]); l[1] = (_Float16)(v1 - (float)h[1]);
  l[2] = (_Float16)(v2 - (float)h[2]); l[3] = (_Float16)(v3 - (float)h[3]);
  l[4] = (_Float16)(v4 - (float)h[4]); l[5] = (_Float16)(v5 - (float)h[5]);
  l[6] = (_Float16)(v6 - (float)h[6]); l[7] = (_Float16)(v7 - (float)h[7]);
}

// ---------------- workspace layout (bytes) ----------------
// xph/xpl: f16 planes, layout [b][y128][kc8][x128][ci16]
#define XPH_OFF 0ull                       // 33,554,432
#define XPL_OFF 33554432ull                // 33,554,432
#define F_OFF   67108864ull                // fp32 [b][c][d]        524,288
#define AO_OFF  67633152ull                // fp32 [b][c][d]        524,288
#define MT_OFF  68157440ull                // fp16 [b][o][d]        262,144
#define WTH_OFF 68419584ull                // fp16 A-frag theta hi  294,912
#define WTL_OFF (WTH_OFF + 294912ull)
#define WPH_OFF (WTL_OFF + 294912ull)
#define WPL_OFF (WPH_OFF + 294912ull)
#define WS_NEED (WPL_OFF + 294912ull)      // 69,599,232

// gram LDS swizzle: [oc][n64] fp32, 4-float chunks XOR-permuted within row
__device__ __forceinline__ int swaddr(int oc, int n) {
  return oc * 64 + (((n >> 2) ^ (oc & 15)) << 2) + (n & 3);
}

// ---------------- weight pre-split into A-frag hi/lo ----------------------
// layout [tap][kc8][oc128][cil16]; ci = kc*16+cil
__global__ __launch_bounds__(256) void k_prep(const float* __restrict__ tw,
                                              const float* __restrict__ pw,
                                              _Float16* __restrict__ wth,
                                              _Float16* __restrict__ wtl,
                                              _Float16* __restrict__ wph,
                                              _Float16* __restrict__ wpl) {
  int which = blockIdx.x >= 576;
  int idx = (blockIdx.x - (which ? 576 : 0)) * 256 + threadIdx.x;  // 0..147455
  int cil = idx & 15;
  int oc  = (idx >> 4) & 127;
  int kc  = (idx >> 11) & 7;
  int tap = idx >> 14;            // 0..8
  int ci = kc * 16 + cil;
  const float* src = which ? pw : tw;
  float v = src[(oc * 128 + ci) * 9 + tap];
  _Float16 h = (_Float16)v;
  _Float16 l = (_Float16)(v - (float)h);
  if (which) { wph[idx] = h; wpl[idx] = l; }
  else       { wth[idx] = h; wtl[idx] = l; }
}

// ---------------- zero f accumulator ---------------------------------------
__global__ __launch_bounds__(256) void k_zero(float* __restrict__ f) {
  f[blockIdx.x * 256 + threadIdx.x] = 0.f;
}

// ---------------- maxpool 2x2 -> pre-split f16 hi/lo planes ----------------
// out layout: [b][y][kc8][x128][ci16] per plane (16B chunks, fully register)
__global__ __launch_bounds__(256) void k_pool(const float* __restrict__ x,
                                              _Float16* __restrict__ xph,
                                              _Float16* __restrict__ xpl) {
  int blk = blockIdx.x;
  int b = blk >> 7, y = blk & 127;
  int t = threadIdx.x;
  int xo = t & 63, ch = t >> 6;   // ch 0..3 -> c in [ch*32, ch*32+32)
  for (int hx = 0; hx < 2; hx++) {
    int xg = hx * 64 + xo;
    const float* xb = x + (size_t)b * CCH * NN + (size_t)(2 * y) * WW2 + 2 * xg;
    float v[32];
#pragma unroll
    for (int i = 0; i < 32; i++) {
      const float* pp = xb + (size_t)(ch * 32 + i) * NN;
      float2 r0 = *(const float2*)pp;
      float2 r1 = *(const float2*)(pp + WW2);
      v[i] = fmaxf(fmaxf(r0.x, r0.y), fmaxf(r1.x, r1.y));
    }
#pragma unroll
    for (int kc2 = 0; kc2 < 2; kc2++) {
      int kc = ch * 2 + kc2;
#pragma unroll
      for (int qq = 0; qq < 2; qq++) {
        half8 hv, lv;
#pragma unroll
        for (int u = 0; u < 8; u++) {
          float vv = v[kc2 * 16 + qq * 8 + u];
          _Float16 hh = (_Float16)vv;
          hv[u] = hh;
          lv[u] = (_Float16)(vv - (float)hh);
        }
        size_t di = (((size_t)(b * 128 + y) * 8 + kc) * 128 + xg) * 16 + qq * 8;
        *(half8*)(xph + di) = hv;
        *(half8*)(xpl + di) = lv;
      }
    }
  }
}

// ---------------- dual 3x3 conv (split-fp16 x3) + fused gram -> f ----------
// LDS: double-buffered 16-ci slices: [buf2][plane2][r3][x130][CSTR]
#define CSTR 20            // f16 per x-slot (40B)
#define PL   7800          // plane stride f16  (3*130*20)
#define BUFS 15600         // buffer stride f16 (2 planes)
__global__ __launch_bounds__(512, 2) void k_conv(
    const _Float16* __restrict__ xph, const _Float16* __restrict__ xpl,
    const _Float16* __restrict__ wth, const _Float16* __restrict__ wtl,
    const _Float16* __restrict__ wph, const _Float16* __restrict__ wpl,
    const float* __restrict__ tb, const float* __restrict__ pb,
    float* __restrict__ f) {
  __shared__ __align__(16) char smem[65536];
  _Float16* xsh = (_Float16*)smem;         // conv phase: 2*15600 f16 = 62,400B
  float* thL = (float*)smem;               // gram phase overlay: [128][64] x2
  float* phL = thL + 8192;

  int blk = blockIdx.x;
  int b = blk >> 7, y = blk & 127;
  int t = threadIdx.x;
  int wave = t >> 6, lane = t & 63;
  int wm = wave & 3, wn = wave >> 2;       // oc-strip(32) x n-half(64)
  int l31 = lane & 31, q = lane >> 5;

  floatx16 aT0 = zero16(), aT1 = zero16(), aP0 = zero16(), aP1 = zero16();

  // zero x-halo slots (x=0 and x=129) for both buffers & planes, once
  if (t < 96) {
    int quad = t & 3;
    int slot = t >> 2;                     // 0..23
    int buf = slot / 12, rem = slot % 12;
    int plane = rem / 6, rem2 = rem % 6;
    int r = rem2 >> 1, side = rem2 & 1;
    half4v z;
    z[0] = (_Float16)0.f; z[1] = (_Float16)0.f;
    z[2] = (_Float16)0.f; z[3] = (_Float16)0.f;
    *(half4v*)(xsh + buf * BUFS + plane * PL + (r * 130 + side * 129) * CSTR + quad * 4) = z;
  }

  // staging: per slice, 1536 16B chunks = 3 per thread
  // ch = t + i*512; combo=ch>>8: r=combo>>1, plane=combo&1; idx=ch&255: x=idx>>1, q=idx&1
  auto stage_load = [&](int kcn, half8 (&st)[3]) {
#pragma unroll
    for (int i = 0; i < 3; i++) {
      int chn = t + i * 512;
      int combo = chn >> 8;
      int r = combo >> 1, plane = combo & 1;
      int idx = chn & 255;
      int xq = idx >> 1, qq = idx & 1;
      int yy = y - 1 + r;
      half8 v;
#pragma unroll
      for (int u = 0; u < 8; u++) v[u] = (_Float16)0.f;
      if ((unsigned)yy < 128u) {
        const _Float16* src = plane ? xpl : xph;
        v = *(const half8*)(src + (((size_t)(b * 128 + yy) * 8 + kcn) * 128 + xq) * 16 + qq * 8);
      }
      st[i] = v;
    }
  };
  auto stage_write = [&](int tbuf, half8 (&st)[3]) {
#pragma unroll
    for (int i = 0; i < 3; i++) {
      int chn = t + i * 512;
      int combo = chn >> 8;
      int r = combo >> 1, plane = combo & 1;
      int idx = chn & 255;
      int xq = idx >> 1, qq = idx & 1;
      int a = tbuf * BUFS + plane * PL + (r * 130 + 1 + xq) * CSTR + qq * 8;
      half4v lo = __builtin_shufflevector(st[i], st[i], 0, 1, 2, 3);
      half4v hi = __builtin_shufflevector(st[i], st[i], 4, 5, 6, 7);
      *(half4v*)(xsh + a) = lo;
      *(half4v*)(xsh + a + 4) = hi;
    }
  };

  // prologue: stage slice 0 into buf 0
  half8 st[3];
  stage_load(0, st);
  stage_write(0, st);
  __syncthreads();

  int xs0 = wn * 64 + l31;
  for (int kc = 0; kc < 8; kc++) {
    int cur = kc & 1;
    // T14: issue next slice's global loads BEFORE compute (latency hides under MFMA)
    if (kc < 7) stage_load(kc + 1, st);
    const _Float16* cb = xsh + cur * BUFS;
#pragma unroll
    for (int tap = 0; tap < 9; tap++) {
      int rr = tap / 3, dxr = tap - rr * 3;
      size_t aoff = (((size_t)(tap * 8 + kc)) * 128 + wm * 32 + l31) * 16 + q * 8;
      half8 ath  = *(const half8*)(wth + aoff);
      half8 atl  = *(const half8*)(wtl + aoff);
      half8 aphh = *(const half8*)(wph + aoff);
      half8 apll = *(const half8*)(wpl + aoff);
      const _Float16* bp = cb + (rr * 130 + xs0 + dxr) * CSTR + q * 8;
      half4v t0 = *(const half4v*)bp;
      half4v t1 = *(const half4v*)(bp + 4);
      half4v t2 = *(const half4v*)(bp + 32 * CSTR);
      half4v t3 = *(const half4v*)(bp + 32 * CSTR + 4);
      half4v t4 = *(const half4v*)(bp + PL);
      half4v t5 = *(const half4v*)(bp + PL + 4);
      half4v t6 = *(const half4v*)(bp + PL + 32 * CSTR);
      half4v t7 = *(const half4v*)(bp + PL + 32 * CSTR + 4);
      half8 bh0 = __builtin_shufflevector(t0, t1, 0, 1, 2, 3, 4, 5, 6, 7);
      half8 bh1 = __builtin_shufflevector(t2, t3, 0, 1, 2, 3, 4, 5, 6, 7);
      half8 bl0 = __builtin_shufflevector(t4, t5, 0, 1, 2, 3, 4, 5, 6, 7);
      half8 bl1 = __builtin_shufflevector(t6, t7, 0, 1, 2, 3, 4, 5, 6, 7);
      __builtin_amdgcn_s_setprio(1);
      aT0 = mfma16(ath, bh0, aT0);  aT1 = mfma16(ath, bh1, aT1);
      aP0 = mfma16(aphh, bh0, aP0); aP1 = mfma16(aphh, bh1, aP1);
      aT0 = mfma16(ath, bl0, aT0);  aT1 = mfma16(ath, bl1, aT1);
      aP0 = mfma16(aphh, bl0, aP0); aP1 = mfma16(aphh, bl1, aP1);
      aT0 = mfma16(atl, bh0, aT0);  aT1 = mfma16(atl, bh1, aT1);
      aP0 = mfma16(apll, bh0, aP0); aP1 = mfma16(apll, bh1, aP1);
      __builtin_amdgcn_s_setprio(0);
    }
    // write-late: staged regs -> other buffer (vmcnt drains here, post-MFMA)
    if (kc < 7) stage_write(cur ^ 1, st);
    __syncthreads();
  }

  // ---- fused gram: f_partial(row y) = theta_row * phi_row^T, K=128 --------
  __syncthreads();                          // defensive; conv reads done
  floatx16 g0 = zero16(), g1 = zero16();
  int tc = wave >> 1, td0 = (wave & 1) * 2; // wave -> 2 tiles of 32x32
  for (int np = 0; np < 2; np++) {          // n-halves of 64
    if (np) __syncthreads();
    if (wn == np) {                         // owning waves dump fragments
#pragma unroll
      for (int r = 0; r < 16; r++) {
        int row = (r & 3) + 8 * (r >> 2) + 4 * q;
        int oc = wm * 32 + row;
        float tv = tb[oc], pv = pb[oc];
        int n0 = l31, n1 = 32 + l31;
        thL[swaddr(oc, n0)] = aT0[r] + tv;
        thL[swaddr(oc, n1)] = aT1[r] + tv;
        phL[swaddr(oc, n0)] = aP0[r] + pv;
        phL[swaddr(oc, n1)] = aP1[r] + pv;
      }
    }
    __syncthreads();
#pragma unroll
    for (int ks = 0; ks < 4; ks++) {        // K=64 in 16-chunks
      int m1 = ks * 4 + q * 2;
      int ca = tc * 32 + l31;
      float4 fa = *(const float4*)(thL + ca * 64 + ((m1 ^ (ca & 15)) << 2));
      float4 fb = *(const float4*)(thL + ca * 64 + (((m1 + 1) ^ (ca & 15)) << 2));
      half8 Ah, Al; split8(fa, fb, Ah, Al);
      int d0 = td0 * 32 + l31;
      int d1 = d0 + 32;
      float4 p0a = *(const float4*)(phL + d0 * 64 + ((m1 ^ (d0 & 15)) << 2));
      float4 p0b = *(const float4*)(phL + d0 * 64 + (((m1 + 1) ^ (d0 & 15)) << 2));
      float4 p1a = *(const float4*)(phL + d1 * 64 + ((m1 ^ (d1 & 15)) << 2));
      float4 p1b = *(const float4*)(phL + d1 * 64 + (((m1 + 1) ^ (d1 & 15)) << 2));
      half8 B0h, B0l; split8(p0a, p0b, B0h, B0l);
      half8 B1h, B1l; split8(p1a, p1b, B1h, B1l);
      g0 = mfma16(Ah, B0h, g0); g0 = mfma16(Ah, B0l, g0); g0 = mfma16(Al, B0h, g0);
      g1 = mfma16(Ah, B1h, g1); g1 = mfma16(Ah, B1l, g1); g1 = mfma16(Al, B1h, g1);
    }
  }
  float* fb_ = f + (size_t)b * 16384;
#pragma unroll
  for (int r = 0; r < 16; r++) {
    int row = (r & 3) + 8 * (r >> 2) + 4 * q;
    int c = tc * 32 + row;
    atomicAdd(fb_ + c * 128 + td0 * 32 + l31, g0[r]);
    atomicAdd(fb_ + c * 128 + (td0 + 1) * 32 + l31, g1[r]);
  }
}

// ---------------- softmax over d --------------------------------------------
__global__ __launch_bounds__(64) void k_softmax(const float* __restrict__ f,
                                                float* __restrict__ aout) {
  int b = blockIdx.x >> 7, c = blockIdx.x & 127;
  int lane = threadIdx.x;
  const float* p = f + ((size_t)b * 128 + c) * 128;
  float s0 = p[lane], s1 = p[lane + 64];
  float m = fmaxf(s0, s1);
  for (int off = 32; off > 0; off >>= 1) m = fmaxf(m, __shfl_xor(m, off, 64));
  float e0 = expf(s0 - m), e1 = expf(s1 - m);
  float s = e0 + e1;
  for (int off = 32; off > 0; off >>= 1) s += __shfl_xor(s, off, 64);
  float inv = 1.f / s;
  float* ao = aout + ((size_t)b * 128 + c) * 128;
  ao[lane] = e0 * inv;
  ao[lane + 64] = e1 * inv;
}

// ---------------- M[b][o][d] = scale[o] * sum_c W[o][c] a[b][c][d] ----------
__global__ __launch_bounds__(256) void k_m(const float* __restrict__ aout,
                                           const float* __restrict__ Ww,
                                           const float* __restrict__ gamma,
                                           const float* __restrict__ var,
                                           _Float16* __restrict__ Mt) {
  __shared__ float as_[128 * 128];
  int b = blockIdx.x >> 3, os = blockIdx.x & 7;
  int t = threadIdx.x;
  const float4* src = (const float4*)(aout + (size_t)b * 16384);
  float4* d4 = (float4*)as_;
  for (int i = 0; i < 16; i++) d4[t + i * 256] = src[t + i * 256];
  __syncthreads();
  int d = t & 127, og = t >> 7;
  float acc[8];
#pragma unroll
  for (int j = 0; j < 8; j++) acc[j] = 0.f;
  for (int c = 0; c < 128; c++) {
    float av = as_[c * 128 + d];
#pragma unroll
    for (int j = 0; j < 8; j++) {
      int o = os * 16 + og * 8 + j;
      acc[j] += Ww[o * 128 + c] * av;
    }
  }
#pragma unroll
  for (int j = 0; j < 8; j++) {
    int o = os * 16 + og * 8 + j;
    float sc = gamma[o] * rsqrtf(var[o] + BN_EPS);
    Mt[((size_t)b * 128 + o) * 128 + d] = (_Float16)(sc * acc[j]);
  }
}

// ---------------- out = M @ X + off[o] + x ----------------------------------
__global__ __launch_bounds__(256, 4) void k_final(
    const float* __restrict__ x, const _Float16* __restrict__ Mt,
    const float* __restrict__ Wb, const float* __restrict__ gamma,
    const float* __restrict__ beta, const float* __restrict__ mean,
    const float* __restrict__ var, float* __restrict__ out) {
  __shared__ __align__(16) _Float16 xt[128 * 132];
  int blk = blockIdx.x;
  int b = blk >> 9, nt = blk & 511;
  int n0 = nt * 128;
  int t = threadIdx.x;
  int wave = t >> 6, lane = t & 63;
  int l31 = lane & 31, q = lane >> 5;
  int nq = t & 7;
  for (int rl = 0; rl < 4; rl++) {
    int dd = (t >> 3) + 32 * rl;
    const float* xr = x + ((size_t)b * CCH + dd) * NN + n0;
    _Float16* dst = xt + dd * 132;
#pragma unroll
    for (int i = 0; i < 4; i++) {
      int f4 = nq + 8 * i;
      float4 v = ((const float4*)xr)[f4];
      half4v hv;
      hv[0] = (_Float16)v.x; hv[1] = (_Float16)v.y;
      hv[2] = (_Float16)v.z; hv[3] = (_Float16)v.w;
      *(half4v*)(dst + f4 * 4) = hv;
    }
  }
  __syncthreads();
  floatx16 a0 = zero16(), a1 = zero16(), a2 = zero16(), a3 = zero16();
  const _Float16* mrow = Mt + ((size_t)b * 128 + wave * 32 + l31) * 128 + q * 8;
  for (int ks = 0; ks < 8; ks++) {
    half8 am = *(const half8*)(mrow + ks * 16);
    int d0 = ks * 16 + q * 8;
    half8 b0, b1, b2, b3;
#pragma unroll
    for (int j = 0; j < 8; j++) {
      const _Float16* xr2 = xt + (d0 + j) * 132 + l31;
      b0[j] = xr2[0];
      b1[j] = xr2[32];
      b2[j] = xr2[64];
      b3[j] = xr2[96];
    }
    a0 = mfma16(am, b0, a0);
    a1 = mfma16(am, b1, a1);
    a2 = mfma16(am, b2, a2);
    a3 = mfma16(am, b3, a3);
  }
#pragma unroll
  for (int r = 0; r < 16; r++) {
    int row = (r & 3) + 8 * (r >> 2) + 4 * q;
    int oc = wave * 32 + row;
    float sc = gamma[oc] * rsqrtf(var[oc] + BN_EPS);
    float off = sc * (Wb[oc] - mean[oc]) + beta[oc];
    size_t base = ((size_t)b * CCH + oc) * NN + n0 + l31;
    out[base]      = a0[r] + off + x[base];
    out[base + 32] = a1[r] + off + x[base + 32];
    out[base + 64] = a2[r] + off + x[base + 64];
    out[base + 96] = a3[r] + off + x[base + 96];
  }
}

extern "C" void kernel_launch(void* const* d_in, const int* in_sizes, int n_in,
                              void* d_out, int out_size, void* d_ws, size_t ws_size,
                              hipStream_t stream) {
  const float* x     = (const float*)d_in[0];
  const float* tw    = (const float*)d_in[1];
  const float* tb    = (const float*)d_in[2];
  const float* pw    = (const float*)d_in[3];
  const float* pb    = (const float*)d_in[4];
  const float* Ww    = (const float*)d_in[5];
  const float* Wb    = (const float*)d_in[6];
  const float* gamma = (const float*)d_in[7];
  const float* beta  = (const float*)d_in[8];
  const float* mean  = (const float*)d_in[9];
  const float* var   = (const float*)d_in[10];
  float* out = (float*)d_out;
  char* ws = (char*)d_ws;
  if (ws_size < WS_NEED) return;

  _Float16* xph  = (_Float16*)(ws + XPH_OFF);
  _Float16* xpl  = (_Float16*)(ws + XPL_OFF);
  float* f       = (float*)(ws + F_OFF);
  float* aout    = (float*)(ws + AO_OFF);
  _Float16* Mt   = (_Float16*)(ws + MT_OFF);
  _Float16* wth  = (_Float16*)(ws + WTH_OFF);
  _Float16* wtl  = (_Float16*)(ws + WTL_OFF);
  _Float16* wph  = (_Float16*)(ws + WPH_OFF);
  _Float16* wpl  = (_Float16*)(ws + WPL_OFF);

  k_prep<<<dim3(1152), dim3(256), 0, stream>>>(tw, pw, wth, wtl, wph, wpl);
  k_pool<<<dim3(1024), dim3(256), 0, stream>>>(x, xph, xpl);
  k_zero<<<dim3(512), dim3(256), 0, stream>>>(f);
  k_conv<<<dim3(1024), dim3(512), 0, stream>>>(xph, xpl, wth, wtl, wph, wpl, tb, pb, f);
  k_softmax<<<dim3(1024), dim3(64), 0, stream>>>(f, aout);
  k_m<<<dim3(64), dim3(256), 0, stream>>>(aout, Ww, gamma, var, Mt);
  k_final<<<dim3(4096), dim3(256), 0, stream>>>(x, Mt, Wb, gamma, beta, mean, var, out);
}